// Round 1
// 367.899 us; speedup vs baseline: 1.0653x; 1.0653x over previous
//
#include <hip/hip_runtime.h>
#include <hip/hip_bf16.h>
#include <math.h>

#define H 128
#define K 20
#define EPB 16        // edges per block (M=16 for MFMA)

// ---- workspace layout (float offsets) ----
#define WS_TBL    0            // merged table: 257 rows x 256 floats {W,B}
#define WS_THM    65792        // 256 merged sorted thresholds
#define WS_CNT    66176        // 1 int: M = nP + nN
#define WSB_HI    67072        // 65536 ushort: em_w1 bf16-hi, B-fragment order
#define WSB_LO    99840        // 65536 ushort: em_w1 bf16-lo

typedef __attribute__((ext_vector_type(8))) short short8;
typedef __attribute__((ext_vector_type(4))) float f32x4;

// DPP-based wave64 sum; result valid in lane 63.
template<int CTRL, int RMASK>
__device__ __forceinline__ float dpp_add(float x) {
  int y = __builtin_amdgcn_update_dpp(0, __float_as_int(x), CTRL, RMASK, 0xf, true);
  return x + __int_as_float(y);
}
__device__ __forceinline__ float wave_sum63(float x) {
  x = dpp_add<0xB1,  0xf>(x);
  x = dpp_add<0x4E,  0xf>(x);
  x = dpp_add<0x141, 0xf>(x);
  x = dpp_add<0x140, 0xf>(x);
  x = dpp_add<0x142, 0xa>(x);
  x = dpp_add<0x143, 0xc>(x);
  return x;
}
__device__ __forceinline__ float bcast63(float x) {
  return __int_as_float(__builtin_amdgcn_readlane(__float_as_int(x), 63));
}

__device__ __forceinline__ unsigned short bfbits(float x) {
  __hip_bfloat16 h = __float2bfloat16(x);
  unsigned short u; __builtin_memcpy(&u, &h, 2); return u;
}
__device__ __forceinline__ float bf2f(unsigned short u) {
  return __uint_as_float(((unsigned)u) << 16);
}

// Single fused aux kernel (769 blocks x 128 threads):
//  blocks 0..256  : locally recompute the threshold sort, then build merged-
//                   table row r = blockIdx (block 0 also publishes THM/CNT).
//  blocks 257..768: pack em_w1 into bf16 hi/lo planes, B-fragment order.
__global__ __launch_bounds__(128) void aux_kernel(
    const float* __restrict__ w1v, const float* __restrict__ b1v,
    const float* __restrict__ w2, const float* __restrict__ b2,
    const float* __restrict__ em_w1, float* __restrict__ ws)
{
  int blk = blockIdx.x;
  int tid = threadIdx.x;
  if (blk < 257) {
    __shared__ float th[H];
    __shared__ int grp[H];
    __shared__ int sidx[2 * H];
    __shared__ int Msh;
    float w = w1v[tid], b = b1v[tid];
    int g = (w > 0.f) ? 0 : ((w < 0.f) ? 1 : 2);   // 0=P, 1=N, 2=Z
    float t = (g == 2) ? 0.f : (-b / w);
    th[tid] = t; grp[tid] = g;
    if (tid == 0) Msh = 0;
    __syncthreads();
    if (g != 2) {
      int r = 0;
      for (int i = 0; i < H; i++)
        if (grp[i] != 2 && (th[i] < t || (th[i] == t && i < tid))) r++;
      sidx[r] = (tid << 1) | (g == 0 ? 1 : 0);     // bit0 = isP
      atomicAdd(&Msh, 1);
      if (blk == 0) ws[WS_THM + r] = t;            // publish for main
    }
    __syncthreads();
    int M = Msh;
    if (blk == 0 && tid == 0) ((int*)(ws + WS_CNT))[0] = M;
    int r = blk;
    if (r > M) return;
    int d = tid;
    // BASE[d] = tp_b2[d] + sum over (w1==0, b1>0) of b1*w2[h][d]
    float accW = 0.f, accB = b2[d];
    for (int i = 0; i < H; i++)
      if (grp[i] == 2 && b1v[i] > 0.f) accB += b1v[i] * w2[i * H + d];
    #pragma unroll 4
    for (int i = 0; i < M; i++) {
      int ent = sidx[i];
      int h = ent >> 1;
      int isP = ent & 1;
      int take = (i < r) ? isP : (1 - isP);
      if (take) {
        float wv = w2[h * H + d];
        accW += w1v[h] * wv;
        accB += b1v[h] * wv;
      }
    }
    ws[WS_TBL + r * 256 + 2 * d + 0] = accW;
    ws[WS_TBL + r * 256 + 2 * d + 1] = accB;
  } else {
    // pack: B-fragment for mfma_f32_16x16x32_bf16:
    // frag (c,kc,lane) elem j = B[k=kc*32+(lane>>4)*8+j][n=c*16+(lane&15)]
    int idx = (blk - 257) * 128 + tid;             // 65536 total
    int j  = idx & 7;
    int l  = (idx >> 3) & 63;
    int kc = (idx >> 9) & 15;
    int c  = idx >> 13;
    int k = kc * 32 + ((l >> 4) * 8) + j;
    int n = c * 16 + (l & 15);
    float x = em_w1[k * H + n];
    unsigned short hb = bfbits(x);
    unsigned short lb = bfbits(x - bf2f(hb));
    ((unsigned short*)(ws + WSB_HI))[idx] = hb;
    ((unsigned short*)(ws + WSB_LO))[idx] = lb;
  }
}

// Attention: each wave owns 4 EDGES; both sides (u,v) concurrently, and TWO
// KEYS per side per iteration -> 4 independent latency chains (gather + DPP
// reduce + softmax). Empty-mask fallback is folded into the main loop: seed
// the mask with all 20 keys and force scores to -1e9 -> online softmax
// degenerates to exactly uniform 1/20 (ss sums to exactly 20.0).
template<int NB>
__device__ __forceinline__ void run_sides(
    int sbase, int b0, int B, int lane,
    const int* __restrict__ edge_index, const int* __restrict__ edge_ts,
    const int* __restrict__ hist_nb, const int* __restrict__ hist_tm,
    const int* __restrict__ hist_sg,
    const float* __restrict__ node_emb, const float* __restrict__ ws,
    float th0, float th1, float th2, float th3,
    float2 se0, float2 se1, float* __restrict__ zbuf)
{
  const float S = 0.088388347648318447f;   // 1/sqrt(128)
  int eBase = sbase >> 1;                  // 4 edges per wave
  // ---- prefetch edge eBase (both sides) ----
  int eN = b0 + eBase;
  int nU = edge_index[eN];
  int nV = edge_index[B + eN];
  int t_n = edge_ts[eN];
  float2 qU_n = *(const float2*)(node_emb + (size_t)nU * H + 2 * lane);
  float2 qV_n = *(const float2*)(node_emb + (size_t)nV * H + 2 * lane);
  int pkU_n = 0, tmU_n = 0, pkV_n = 0, tmV_n = 0;
  if (lane < K) {
    pkU_n = (hist_nb[nU * K + lane] << 1) | hist_sg[nU * K + lane];
    tmU_n = hist_tm[nU * K + lane];
    pkV_n = (hist_nb[nV * K + lane] << 1) | hist_sg[nV * K + lane];
    tmV_n = hist_tm[nV * K + lane];
  }

  #pragma unroll 1
  for (int p = 0; p < 4; p++) {
    int e = eBase + p;
    int tC = t_n;
    float2 qU = qU_n, qV = qV_n;
    int pkU = pkU_n, tmU = tmU_n, pkV = pkV_n, tmV = tmV_n;
    if (p < 3) {
      int e2 = b0 + e + 1;
      int nU2 = edge_index[e2];
      int nV2 = edge_index[B + e2];
      t_n = edge_ts[e2];
      qU_n = *(const float2*)(node_emb + (size_t)nU2 * H + 2 * lane);
      qV_n = *(const float2*)(node_emb + (size_t)nV2 * H + 2 * lane);
      if (lane < K) {
        pkU_n = (hist_nb[nU2 * K + lane] << 1) | hist_sg[nU2 * K + lane];
        tmU_n = hist_tm[nU2 * K + lane];
        pkV_n = (hist_nb[nV2 * K + lane] << 1) | hist_sg[nV2 * K + lane];
        tmV_n = hist_tm[nV2 * K + lane];
      }
    }

    unsigned long long mU0 = __ballot((lane < K) && (tmU < tC) && (pkU >= 0));
    unsigned long long mV0 = __ballot((lane < K) && (tmV < tC) && (pkV >= 0));
    // fold fallback: empty mask -> walk all 20 keys with forced score -1e9
    bool fU = (mU0 == 0), fV = (mV0 == 0);
    unsigned long long mU = fU ? 0xFFFFFull : mU0;
    unsigned long long mV = fV ? 0xFFFFFull : mV0;
    float qUx = qU.x * S, qUy = qU.y * S;
    float qVx = qV.x * S, qVy = qV.y * S;

    float mxU = -3.0e38f, ssU = 0.f, zU0 = 0.f, zU1 = 0.f;
    float mxV = -3.0e38f, ssV = 0.f, zV0 = 0.f, zV1 = 0.f;
    while (mU | mV) {
      bool vUa = mU != 0; int kUa = vUa ? (__ffsll((long long)mU) - 1) : 0; mU &= mU - 1;
      bool vUb = mU != 0; int kUb = vUb ? (__ffsll((long long)mU) - 1) : 0; mU &= mU - 1;
      bool vVa = mV != 0; int kVa = vVa ? (__ffsll((long long)mV) - 1) : 0; mV &= mV - 1;
      bool vVb = mV != 0; int kVb = vVb ? (__ffsll((long long)mV) - 1) : 0; mV &= mV - 1;

      int tmkUa = __builtin_amdgcn_readlane(tmU, kUa);
      int pkkUa = __builtin_amdgcn_readlane(pkU, kUa);
      int tmkUb = __builtin_amdgcn_readlane(tmU, kUb);
      int pkkUb = __builtin_amdgcn_readlane(pkU, kUb);
      int tmkVa = __builtin_amdgcn_readlane(tmV, kVa);
      int pkkVa = __builtin_amdgcn_readlane(pkV, kVa);
      int tmkVb = __builtin_amdgcn_readlane(tmV, kVb);
      int pkkVb = __builtin_amdgcn_readlane(pkV, kVb);

      float dUa = (float)tC - (float)tmkUa;
      float dUb = (float)tC - (float)tmkUb;
      float dVa = (float)tC - (float)tmkVa;
      float dVb = (float)tC - (float)tmkVb;

      int rUa = __popcll(__ballot(th0 < dUa)) + __popcll(__ballot(th1 < dUa));
      int rUb = __popcll(__ballot(th0 < dUb)) + __popcll(__ballot(th1 < dUb));
      int rVa = __popcll(__ballot(th0 < dVa)) + __popcll(__ballot(th1 < dVa));
      int rVb = __popcll(__ballot(th0 < dVb)) + __popcll(__ballot(th1 < dVb));
      if (NB == 4) {
        rUa += __popcll(__ballot(th2 < dUa)) + __popcll(__ballot(th3 < dUa));
        rUb += __popcll(__ballot(th2 < dUb)) + __popcll(__ballot(th3 < dUb));
        rVa += __popcll(__ballot(th2 < dVa)) + __popcll(__ballot(th3 < dVa));
        rVb += __popcll(__ballot(th2 < dVb)) + __popcll(__ballot(th3 < dVb));
      }

      // 4 independent table rows + 4 independent embedding rows in flight
      const float4 tUa = *(const float4*)(ws + WS_TBL + rUa * 256 + 4 * lane);
      const float4 tUb = *(const float4*)(ws + WS_TBL + rUb * 256 + 4 * lane);
      const float4 tVa = *(const float4*)(ws + WS_TBL + rVa * 256 + 4 * lane);
      const float4 tVb = *(const float4*)(ws + WS_TBL + rVb * 256 + 4 * lane);
      int nUa = (pkkUa < 0) ? 0 : (pkkUa >> 1);
      int nUb = (pkkUb < 0) ? 0 : (pkkUb >> 1);
      int nVa = (pkkVa < 0) ? 0 : (pkkVa >> 1);
      int nVb = (pkkVb < 0) ? 0 : (pkkVb >> 1);
      float2 eUa = *(const float2*)(node_emb + (size_t)nUa * H + 2 * lane);
      float2 eUb = *(const float2*)(node_emb + (size_t)nUb * H + 2 * lane);
      float2 eVa = *(const float2*)(node_emb + (size_t)nVa * H + 2 * lane);
      float2 eVb = *(const float2*)(node_emb + (size_t)nVb * H + 2 * lane);

      float kUa0 = eUa.x + ((pkkUa & 1) ? se1.x : se0.x) + dUa * tUa.x + tUa.y;
      float kUa1 = eUa.y + ((pkkUa & 1) ? se1.y : se0.y) + dUa * tUa.z + tUa.w;
      float kUb0 = eUb.x + ((pkkUb & 1) ? se1.x : se0.x) + dUb * tUb.x + tUb.y;
      float kUb1 = eUb.y + ((pkkUb & 1) ? se1.y : se0.y) + dUb * tUb.z + tUb.w;
      float kVa0 = eVa.x + ((pkkVa & 1) ? se1.x : se0.x) + dVa * tVa.x + tVa.y;
      float kVa1 = eVa.y + ((pkkVa & 1) ? se1.y : se0.y) + dVa * tVa.z + tVa.w;
      float kVb0 = eVb.x + ((pkkVb & 1) ? se1.x : se0.x) + dVb * tVb.x + tVb.y;
      float kVb1 = eVb.y + ((pkkVb & 1) ? se1.y : se0.y) + dVb * tVb.z + tVb.w;

      float pUa = wave_sum63(qUx * kUa0 + qUy * kUa1);
      float pUb = wave_sum63(qUx * kUb0 + qUy * kUb1);
      float pVa = wave_sum63(qVx * kVa0 + qVy * kVa1);
      float pVb = wave_sum63(qVx * kVb0 + qVy * kVb1);

      float sUa = (vUa && !fU) ? bcast63(pUa) : -1e9f;
      float sUb = (vUb && !fU) ? bcast63(pUb) : -1e9f;
      float sVa = (vVa && !fV) ? bcast63(pVa) : -1e9f;
      float sVb = (vVb && !fV) ? bcast63(pVb) : -1e9f;

      float mnU = fmaxf(mxU, fmaxf(sUa, sUb));
      float alU = __expf(mxU - mnU);
      float paU = __expf(sUa - mnU);
      float pbU = __expf(sUb - mnU);
      ssU = ssU * alU + paU + pbU;
      zU0 = zU0 * alU + paU * kUa0 + pbU * kUb0;
      zU1 = zU1 * alU + paU * kUa1 + pbU * kUb1;
      mxU = mnU;

      float mnV = fmaxf(mxV, fmaxf(sVa, sVb));
      float alV = __expf(mxV - mnV);
      float paV = __expf(sVa - mnV);
      float pbV = __expf(sVb - mnV);
      ssV = ssV * alV + paV + pbV;
      zV0 = zV0 * alV + paV * kVa0 + pbV * kVb0;
      zV1 = zV1 * alV + paV * kVa1 + pbV * kVb1;
      mxV = mnV;
    }

    // unified normalize: forced-uniform sides have ss == 20.0 exactly
    float invU = 1.f / ssU; zU0 *= invU; zU1 *= invU;
    float invV = 1.f / ssV; zV0 *= invV; zV1 *= invV;

    int sw = (e & 7) << 1;
    int ccU = lane ^ sw;
    int ccV = (64 + lane) ^ sw;
    *(float2*)&zbuf[(e << 8) + (ccU << 1)] = make_float2(zU0, zU1);
    *(float2*)&zbuf[(e << 8) + (ccV << 1)] = make_float2(zV0, zV1);
  }
}

// Main fused kernel: 4 waves/block, each wave owns 4 edges (8 sides) with
// dual-side + dual-key ILP (4 chains) in the attention phase.
// bounds(256,4): known no-spill regime. zu/zv XOR-swizzled in 16 KB LDS;
// MLP layer 1 via split-bf16 MFMA with derived columns built on the fly.
__global__ __launch_bounds__(256, 4) void tgat_main_kernel(
    const int* __restrict__ edge_index, const int* __restrict__ edge_ts,
    const int* __restrict__ hist_nb, const int* __restrict__ hist_tm,
    const int* __restrict__ hist_sg,
    const float* __restrict__ node_emb, const float* __restrict__ sign_emb,
    const float* __restrict__ em_b1,
    const float* __restrict__ em_w2, const float* __restrict__ em_b2,
    const float* __restrict__ ws, float* __restrict__ out, int B)
{
  // zbuf rows = 16 edges, 256 floats (zu|zv) per row, float2-chunk XOR swizzle:
  // logical chunk c of row e stored at chunk c ^ ((e&7)<<1). 16 KB total.
  __shared__ __align__(16) float zbuf[EPB * 256];

  int tid = threadIdx.x;
  int lane = tid & 63;
  int wv = __builtin_amdgcn_readfirstlane(tid >> 6);
  int b0 = blockIdx.x * EPB;

  int M = ((const int*)(ws + WS_CNT))[0];
  float th0 = (lane       < M) ? ws[WS_THM + lane      ] : 3.0e38f;
  float th1 = (lane + 64  < M) ? ws[WS_THM + lane + 64 ] : 3.0e38f;
  float2 se0 = *(const float2*)(sign_emb + 2 * lane);
  float2 se1 = *(const float2*)(sign_emb + H + 2 * lane);

  int sbase = wv * 8;
  if (M <= 128) {
    run_sides<2>(sbase, b0, B, lane, edge_index, edge_ts, hist_nb, hist_tm,
                 hist_sg, node_emb, ws, th0, th1, 3.0e38f, 3.0e38f,
                 se0, se1, zbuf);
  } else {
    float th2 = (lane + 128 < M) ? ws[WS_THM + lane + 128] : 3.0e38f;
    float th3 = (lane + 192 < M) ? ws[WS_THM + lane + 192] : 3.0e38f;
    run_sides<4>(sbase, b0, B, lane, edge_index, edge_ts, hist_nb, hist_tm,
                 hist_sg, node_emb, ws, th0, th1, th2, th3,
                 se0, se1, zbuf);
  }
  __syncthreads();

  // ---- MLP layer 1 via split-bf16 MFMA: hid[16][128] = feat[16][512] @ em_w1
  // feat regions: [zu | zv | |zu-zv| | zu*zv], built on the fly from zbuf.
  const unsigned short* whi = (const unsigned short*)(ws + WSB_HI);
  const unsigned short* wlo = (const unsigned short*)(ws + WSB_LO);
  int c0 = 2 * wv;
  int m_ = lane & 15;
  int qd = lane >> 4;
  int sw = (m_ & 7) << 1;
  const float* zrow = zbuf + (m_ << 8);
  f32x4 acc0 = {0.f, 0.f, 0.f, 0.f};
  f32x4 acc1 = {0.f, 0.f, 0.f, 0.f};
  #pragma unroll
  for (int kc = 0; kc < 16; kc++) {
    const int reg = kc >> 2;
    int cb = (kc & 3) * 16 + qd * 4;     // base chunk within a 128-dim region
    float av[8];
    if (reg == 0) {
      float4 A0 = *(const float4*)(zrow + (((cb    ) ^ sw) << 1));
      float4 A1 = *(const float4*)(zrow + (((cb + 2) ^ sw) << 1));
      av[0]=A0.x; av[1]=A0.y; av[2]=A0.z; av[3]=A0.w;
      av[4]=A1.x; av[5]=A1.y; av[6]=A1.z; av[7]=A1.w;
    } else if (reg == 1) {
      float4 A0 = *(const float4*)(zrow + (((cb + 64) ^ sw) << 1));
      float4 A1 = *(const float4*)(zrow + (((cb + 66) ^ sw) << 1));
      av[0]=A0.x; av[1]=A0.y; av[2]=A0.z; av[3]=A0.w;
      av[4]=A1.x; av[5]=A1.y; av[6]=A1.z; av[7]=A1.w;
    } else {
      float4 U0 = *(const float4*)(zrow + (((cb    ) ^ sw) << 1));
      float4 U1 = *(const float4*)(zrow + (((cb + 2) ^ sw) << 1));
      float4 V0 = *(const float4*)(zrow + (((cb + 64) ^ sw) << 1));
      float4 V1 = *(const float4*)(zrow + (((cb + 66) ^ sw) << 1));
      float uu[8] = {U0.x,U0.y,U0.z,U0.w,U1.x,U1.y,U1.z,U1.w};
      float vvv[8] = {V0.x,V0.y,V0.z,V0.w,V1.x,V1.y,V1.z,V1.w};
      if (reg == 2) {
        #pragma unroll
        for (int j = 0; j < 8; j++) av[j] = fabsf(uu[j] - vvv[j]);
      } else {
        #pragma unroll
        for (int j = 0; j < 8; j++) av[j] = uu[j] * vvv[j];
      }
    }
    // split-bf16 A fragments: hi = bit-truncation (v_perm pack, 1 op/pair),
    // lo = exact residual (Sterbenz) rounded-ne as a packed pair.
    union { short8 v; unsigned u[4]; } ahi, alo;
    #pragma unroll
    for (int j = 0; j < 4; j++) {
      unsigned b0u = __float_as_uint(av[2 * j]);
      unsigned b1u = __float_as_uint(av[2 * j + 1]);
      ahi.u[j] = __builtin_amdgcn_perm(b1u, b0u, 0x07060302u);
      float l0 = av[2 * j]     - __uint_as_float(b0u & 0xFFFF0000u);
      float l1 = av[2 * j + 1] - __uint_as_float(b1u & 0xFFFF0000u);
      __hip_bfloat162 lp = __float22bfloat162_rn(make_float2(l0, l1));
      __builtin_memcpy(&alo.u[j], &lp, 4);
    }
    int f0 = (((c0    ) * 16 + kc) * 64 + lane) * 8;
    int f1 = (((c0 + 1) * 16 + kc) * 64 + lane) * 8;
    short8 bh0 = *(const short8*)(whi + f0);
    short8 bl0 = *(const short8*)(wlo + f0);
    short8 bh1 = *(const short8*)(whi + f1);
    short8 bl1 = *(const short8*)(wlo + f1);
    acc0 = __builtin_amdgcn_mfma_f32_16x16x32_bf16(ahi.v, bh0, acc0, 0, 0, 0);
    acc0 = __builtin_amdgcn_mfma_f32_16x16x32_bf16(ahi.v, bl0, acc0, 0, 0, 0);
    acc0 = __builtin_amdgcn_mfma_f32_16x16x32_bf16(alo.v, bh0, acc0, 0, 0, 0);
    acc1 = __builtin_amdgcn_mfma_f32_16x16x32_bf16(ahi.v, bh1, acc1, 0, 0, 0);
    acc1 = __builtin_amdgcn_mfma_f32_16x16x32_bf16(ahi.v, bl1, acc1, 0, 0, 0);
    acc1 = __builtin_amdgcn_mfma_f32_16x16x32_bf16(alo.v, bh1, acc1, 0, 0, 0);
  }
  __syncthreads();   // all A-reads of zbuf complete before overlay reuse

  // bias + relu, write hid into zbuf overlay (stride 132)
  float* hp = zbuf;
  float eb0 = em_b1[c0 * 16 + m_];
  float eb1 = em_b1[(c0 + 1) * 16 + m_];
  #pragma unroll
  for (int r = 0; r < 4; r++) {
    int edge = qd * 4 + r;
    hp[edge * 132 + c0 * 16 + m_]       = fmaxf(acc0[r] + eb0, 0.f);
    hp[edge * 132 + (c0 + 1) * 16 + m_] = fmaxf(acc1[r] + eb1, 0.f);
  }
  __syncthreads();

  // ---- layer 2: logits = hid @ em_w2 + em_b2 ; wave wv does edges wv*4..+3
  float2 w2v = *(const float2*)(em_w2 + 2 * lane);
  float bias2 = em_b2[0];
  #pragma unroll
  for (int i = 0; i < 4; i++) {
    int e = wv * 4 + i;
    int b = b0 + e;
    float2 hv = *(const float2*)(hp + e * 132 + 2 * lane);
    float p = wave_sum63(hv.x * w2v.x + hv.y * w2v.y);
    float ps = bcast63(p);
    if (lane == 0 && b < B) out[b] = ps + bias2;
  }
}

extern "C" void kernel_launch(void* const* d_in, const int* in_sizes, int n_in,
                              void* d_out, int out_size, void* d_ws, size_t ws_size,
                              hipStream_t stream)
{
  (void)n_in; (void)out_size; (void)ws_size;
  const int* edge_index = (const int*)d_in[0];
  const int* edge_ts    = (const int*)d_in[1];
  const int* hist_nb    = (const int*)d_in[2];
  const int* hist_tm    = (const int*)d_in[3];
  const int* hist_sg    = (const int*)d_in[4];
  const float* node_emb = (const float*)d_in[5];
  const float* sign_emb = (const float*)d_in[6];
  const float* tp_w1    = (const float*)d_in[7];
  const float* tp_b1    = (const float*)d_in[8];
  const float* tp_w2    = (const float*)d_in[9];
  const float* tp_b2    = (const float*)d_in[10];
  const float* em_w1    = (const float*)d_in[11];
  const float* em_b1    = (const float*)d_in[12];
  const float* em_w2    = (const float*)d_in[13];
  const float* em_b2    = (const float*)d_in[14];
  float* out = (float*)d_out;
  float* ws  = (float*)d_ws;
  int B = in_sizes[1];

  hipLaunchKernelGGL(aux_kernel, dim3(769), dim3(128), 0, stream,
                     tp_w1, tp_b1, tp_w2, tp_b2, em_w1, ws);
  int grid = (B + EPB - 1) / EPB;
  hipLaunchKernelGGL(tgat_main_kernel, dim3(grid), dim3(256), 0, stream,
                     edge_index, edge_ts, hist_nb, hist_tm, hist_sg,
                     node_emb, sign_emb, em_b1, em_w2, em_b2, ws, out, B);
}